// Round 3
// baseline (962.983 us; speedup 1.0000x reference)
//
#include <hip/hip_runtime.h>
#include <stdint.h>

// DCNv2 fused forward (B=8, C=256, H=W=64, OC=256, 3x3, pad=1, stride=1, DG=1)
// R8 BISECT: force the simple single-kernel path (historical R3 structure,
// fp16 hi/lo 3-product numerics). No workspace, no prep kernels, no pipeline.
// Purpose: split {shared core correct, main-path extras buggy} from
// {shared core / harness-model wrong}. See session journal.

typedef __attribute__((ext_vector_type(8))) _Float16 half8;
typedef __attribute__((ext_vector_type(2))) __fp16 fp16x2;
typedef __attribute__((ext_vector_type(4))) float floatx4;
typedef __attribute__((ext_vector_type(4))) unsigned int uintx4;

#define MFMA16(A, B, C) __builtin_amdgcn_mfma_f32_16x16x32_f16(A, B, C, 0, 0, 0)

// fp16 hi/lo split of pre-scaled weight value -> 16-bit patterns
__device__ __forceinline__ void split_f16_bits(float v, unsigned int& h, unsigned int& l) {
    _Float16 hf = (_Float16)v;               // v_cvt_f16_f32 (RNE)
    float hff = (float)hf;                   // exact
    _Float16 lf = (_Float16)(v - hff);       // residual, RNE
    union { _Float16 f; unsigned short s; } a, b;
    a.f = hf; b.f = lf;
    h = a.s; l = b.s;
}

// split 8 cols values -> packed fp16 hi/lo pairs (pkrtz: 1 instr per 2 values)
__device__ __forceinline__ void split_pack8(const float* vals, uintx4& pkH, uintx4& pkL) {
#pragma unroll
    for (int p = 0; p < 4; p++) {
        float v0 = vals[2 * p], v1 = vals[2 * p + 1];
        fp16x2 h = __builtin_amdgcn_cvt_pkrtz(v0, v1);      // RTZ hi pair
        float h0 = (float)h[0], h1 = (float)h[1];           // exact back-convert
        fp16x2 l = __builtin_amdgcn_cvt_pkrtz(v0 - h0, v1 - h1);  // lo pair
        union { fp16x2 v; unsigned int u; } ch, cl;
        ch.v = h; cl.v = l;
        pkH[p] = ch.u;
        pkL[p] = cl.u;
    }
}

__device__ __forceinline__ void mk_coords(int tap, int ho, int wo,
    float offy, float offx, float m,
    int& yx00, int& yx01, int& yx10, int& yx11,
    float& w00, float& w01, float& w10, float& w11) {
    float py = (float)(tap / 3) + (float)(ho - 1) + offy;
    float px = (float)(tap % 3) + (float)(wo - 1) + offx;
    float y0f = floorf(py), x0f = floorf(px);
    float wy1 = py - y0f, wx1 = px - x0f;
    float wy0 = 1.f - wy1, wx0 = 1.f - wx1;
    int y0 = (int)y0f, x0 = (int)x0f, y1 = y0 + 1, x1 = x0 + 1;
    bool vy0 = (y0 >= 0) && (y0 < 64), vy1 = (y1 >= 0) && (y1 < 64);
    bool vx0 = (x0 >= 0) && (x0 < 64), vx1 = (x1 >= 0) && (x1 < 64);
    int cy0 = min(max(y0, 0), 63), cy1 = min(max(y1, 0), 63);
    int cx0 = min(max(x0, 0), 63), cx1 = min(max(x1, 0), 63);
    yx00 = cy0 * 64 + cx0; yx01 = cy0 * 64 + cx1;
    yx10 = cy1 * 64 + cx0; yx11 = cy1 * 64 + cx1;
    w00 = wy0 * wx0 * m * ((vy0 && vx0) ? 1.f : 0.f);
    w01 = wy0 * wx1 * m * ((vy0 && vx1) ? 1.f : 0.f);
    w10 = wy1 * wx0 * m * ((vy1 && vx0) ? 1.f : 0.f);
    w11 = wy1 * wx1 * m * ((vy1 && vx1) ? 1.f : 0.f);
}

// ---- single-kernel path: unpipelined, direct reads, fp16 hi/lo scheme ----
__global__ __launch_bounds__(256, 2) void k_dcn_fb(
    const float* __restrict__ x, const float* __restrict__ offset,
    const float* __restrict__ mask, const float* __restrict__ weight,
    const float* __restrict__ bias, float* __restrict__ out)
{
    __shared__ __align__(16) unsigned short AsH[256 * 40];
    __shared__ __align__(16) unsigned short AsL[256 * 40];
    __shared__ __align__(16) unsigned short BsH[64 * 40];
    __shared__ __align__(16) unsigned short BsL[64 * 40];
    __shared__ int cY[64][4];
    __shared__ float cW[64][4];

    const int t = threadIdx.x;
    const int tile = blockIdx.x;   // 512
    const int b = tile >> 6;
    const int ho = tile & 63;
    const int lane = t & 63, wid = t >> 6, quad = lane >> 4, l15 = lane & 15;
    const int gpos = t >> 2, gseg = t & 3;

    floatx4 acc[4][4];
#pragma unroll
    for (int i = 0; i < 4; i++)
#pragma unroll
        for (int j = 0; j < 4; j++) acc[i][j] = (floatx4){0.f, 0.f, 0.f, 0.f};

    for (int ktap = 0; ktap < 9; ++ktap) {
        __syncthreads();
        if (t < 64) {
            int wo = t;
            int spos = (ho << 6) + wo;
            float offy = offset[(((size_t)(b * 18 + 2 * ktap)) << 12) + spos];
            float offx = offset[(((size_t)(b * 18 + 2 * ktap + 1)) << 12) + spos];
            float m = mask[(((size_t)(b * 9 + ktap)) << 12) + spos];
            int c0, c1, c2, c3; float u0, u1, u2, u3;
            mk_coords(ktap, ho, wo, offy, offx, m, c0, c1, c2, c3, u0, u1, u2, u3);
            cY[t][0] = c0; cY[t][1] = c1; cY[t][2] = c2; cY[t][3] = c3;
            cW[t][0] = u0; cW[t][1] = u1; cW[t][2] = u2; cW[t][3] = u3;
        }
        __syncthreads();
        const int yx00 = cY[gpos][0], yx01 = cY[gpos][1];
        const int yx10 = cY[gpos][2], yx11 = cY[gpos][3];
        const float w00 = cW[gpos][0], w01 = cW[gpos][1];
        const float w10 = cW[gpos][2], w11 = cW[gpos][3];

        for (int cs = 0; cs < 8; ++cs) {
            const int c0 = cs << 5;
            {
                const float* wp = weight + (size_t)t * 2304 + (size_t)c0 * 9 + ktap;
#pragma unroll
                for (int kj = 0; kj < 32; kj += 2) {
                    unsigned int h0, l0u, h1, l1u;
                    split_f16_bits(wp[kj * 9] * 64.f, h0, l0u);
                    split_f16_bits(wp[kj * 9 + 9] * 64.f, h1, l1u);
                    *(unsigned int*)&AsH[t * 40 + kj] = h0 | (h1 << 16);
                    *(unsigned int*)&AsL[t * 40 + kj] = l0u | (l1u << 16);
                }
            }
            {
                const int cb = c0 + (gseg << 3);
                const float* xg = x + ((size_t)b << 20);
                float vals[8];
#pragma unroll
                for (int j = 0; j < 8; j++) {
                    const float* xc = xg + ((size_t)(cb + j) << 12);
                    vals[j] = w00 * xc[yx00] + w01 * xc[yx01] +
                              w10 * xc[yx10] + w11 * xc[yx11];
                }
                uintx4 pkH, pkL;
                split_pack8(vals, pkH, pkL);
                *(uintx4*)&BsH[gpos * 40 + (gseg << 3)] = pkH;
                *(uintx4*)&BsL[gpos * 40 + (gseg << 3)] = pkL;
            }
            __syncthreads();
            half8 aH[4], aL[4], bH[4], bL[4];
#pragma unroll
            for (int i = 0; i < 4; i++) {
                const int rowA = (wid << 6) + (i << 4) + l15;
                aH[i] = *(const half8*)&AsH[rowA * 40 + (quad << 3)];
                aL[i] = *(const half8*)&AsL[rowA * 40 + (quad << 3)];
            }
#pragma unroll
            for (int j = 0; j < 4; j++) {
                const int rowB = (j << 4) + l15;
                bH[j] = *(const half8*)&BsH[rowB * 40 + (quad << 3)];
                bL[j] = *(const half8*)&BsL[rowB * 40 + (quad << 3)];
            }
#pragma unroll
            for (int i = 0; i < 4; i++)
#pragma unroll
                for (int j = 0; j < 4; j++) {
                    acc[i][j] = MFMA16(aH[i], bH[j], acc[i][j]);
                    acc[i][j] = MFMA16(aL[i], bH[j], acc[i][j]);
                    acc[i][j] = MFMA16(aH[i], bL[j], acc[i][j]);
                }
            __syncthreads();
        }
    }
    float* outb = out + ((size_t)b << 20);
    const int posbase = ho << 6;
#pragma unroll
    for (int i = 0; i < 4; i++) {
        const int ocb = (wid << 6) + (i << 4) + (quad << 2);
#pragma unroll
        for (int r = 0; r < 4; r++) {
            const float bv = bias[ocb + r];
#pragma unroll
            for (int j = 0; j < 4; j++) {
                const int pos = posbase + (j << 4) + l15;
                outb[((size_t)(ocb + r) << 12) + pos] = acc[i][j][r] * 0.015625f + bv;
            }
        }
    }
}

extern "C" void kernel_launch(void* const* d_in, const int* in_sizes, int n_in,
                              void* d_out, int out_size, void* d_ws, size_t ws_size,
                              hipStream_t stream) {
    const float* x      = (const float*)d_in[0];
    const float* offset = (const float*)d_in[1];
    const float* mask   = (const float*)d_in[2];
    const float* weight = (const float*)d_in[3];
    const float* bias   = (const float*)d_in[4];
    float* out = (float*)d_out;

    // R8 bisect: force the simple proven-structure path unconditionally.
    (void)d_ws; (void)ws_size;
    k_dcn_fb<<<512, 256, 0, stream>>>(x, offset, mask, weight, bias, out);
}

// Round 4
// 218.657 us; speedup vs baseline: 4.4041x; 4.4041x over previous
//
#include <hip/hip_runtime.h>
#include <stdint.h>

// DCNv2 fused forward (B=8, C=256, H=W=64, OC=256, 3x3, pad=1, stride=1, DG=1)
// R9 BISECT-B: un-pipelined loop (proven structure: gen-B -> barrier -> MFMA ->
// barrier, single LDS buffer, no prefetch/dbuf) fed by the prep kernels:
//   A: register dwordx4 loads from pre-split bw2 (L2-hot)
//   B: corners from transposed xtf, 528-stride Bs LDS layout, per-thread coords
// Tests ALL data-layout machinery while excluding ALL pipeline scheduling.
// fp16 hi/lo 3-product numerics (weights x64, epilogue /64) — R8-proven.

typedef __attribute__((ext_vector_type(8))) _Float16 half8;
typedef __attribute__((ext_vector_type(2))) __fp16 fp16x2;
typedef __attribute__((ext_vector_type(4))) float floatx4;
typedef __attribute__((ext_vector_type(4))) unsigned int uintx4;

#define MFMA16(A, B, C) __builtin_amdgcn_mfma_f32_16x16x32_f16(A, B, C, 0, 0, 0)

__device__ __forceinline__ void split_f16_bits(float v, unsigned int& h, unsigned int& l) {
    _Float16 hf = (_Float16)v;               // v_cvt_f16_f32 (RNE)
    float hff = (float)hf;                   // exact
    _Float16 lf = (_Float16)(v - hff);       // residual, RNE
    union { _Float16 f; unsigned short s; } a, b;
    a.f = hf; b.f = lf;
    h = a.s; l = b.s;
}

__device__ __forceinline__ void split_pack8(const float* vals, uintx4& pkH, uintx4& pkL) {
#pragma unroll
    for (int p = 0; p < 4; p++) {
        float v0 = vals[2 * p], v1 = vals[2 * p + 1];
        fp16x2 h = __builtin_amdgcn_cvt_pkrtz(v0, v1);      // RTZ hi pair
        float h0 = (float)h[0], h1 = (float)h[1];           // exact back-convert
        fp16x2 l = __builtin_amdgcn_cvt_pkrtz(v0 - h0, v1 - h1);  // lo pair
        union { fp16x2 v; unsigned int u; } ch, cl;
        ch.v = h; cl.v = l;
        pkH[p] = ch.u;
        pkL[p] = cl.u;
    }
}

__device__ __forceinline__ void mk_coords(int tap, int ho, int wo,
    float offy, float offx, float m,
    int& yx00, int& yx01, int& yx10, int& yx11,
    float& w00, float& w01, float& w10, float& w11) {
    float py = (float)(tap / 3) + (float)(ho - 1) + offy;
    float px = (float)(tap % 3) + (float)(wo - 1) + offx;
    float y0f = floorf(py), x0f = floorf(px);
    float wy1 = py - y0f, wx1 = px - x0f;
    float wy0 = 1.f - wy1, wx0 = 1.f - wx1;
    int y0 = (int)y0f, x0 = (int)x0f, y1 = y0 + 1, x1 = x0 + 1;
    bool vy0 = (y0 >= 0) && (y0 < 64), vy1 = (y1 >= 0) && (y1 < 64);
    bool vx0 = (x0 >= 0) && (x0 < 64), vx1 = (x1 >= 0) && (x1 < 64);
    int cy0 = min(max(y0, 0), 63), cy1 = min(max(y1, 0), 63);
    int cx0 = min(max(x0, 0), 63), cx1 = min(max(x1, 0), 63);
    yx00 = cy0 * 64 + cx0; yx01 = cy0 * 64 + cx1;
    yx10 = cy1 * 64 + cx0; yx11 = cy1 * 64 + cx1;
    w00 = wy0 * wx0 * m * ((vy0 && vx0) ? 1.f : 0.f);
    w01 = wy0 * wx1 * m * ((vy0 && vx1) ? 1.f : 0.f);
    w10 = wy1 * wx0 * m * ((vy1 && vx0) ? 1.f : 0.f);
    w11 = wy1 * wx1 * m * ((vy1 && vx1) ? 1.f : 0.f);
}

// ---- prep: x (8,256,64,64) f32 -> xtf (8,4096,256) f32, tiled transpose ----
__global__ __launch_bounds__(256) void k_prep_xt(const float* __restrict__ x,
                                                 float* __restrict__ xtf) {
    __shared__ float T[64][65];
    const int blk = blockIdx.x;       // 2048
    const int b = blk >> 8;
    const int ct = (blk >> 6) & 3;
    const int tt = blk & 63;
    const int t = threadIdx.x;
    const int jj = t & 63, i4 = t >> 6;
    const float* xb = x + ((size_t)b << 20);
#pragma unroll 4
    for (int ii = 0; ii < 16; ii++) {
        int i = ii * 4 + i4;
        T[i][jj] = xb[((size_t)(ct * 64 + i) << 12) + tt * 64 + jj];
    }
    __syncthreads();
    float* ob = xtf + ((size_t)b << 20);
#pragma unroll 4
    for (int ii = 0; ii < 16; ii++) {
        int jo = ii * 4 + i4;
        ob[((size_t)(tt * 64 + jo) << 8) + ct * 64 + jj] = T[jj][jo];
    }
}

// ---- prep: weight*64 -> bw2[step72][hl2][chunk4][oc256][8k] fp16 ----
__global__ __launch_bounds__(256) void k_prep_w2(const float* __restrict__ w,
                                                 unsigned short* __restrict__ bw2) {
    int tid = blockIdx.x * 256 + threadIdx.x;   // 72*16384
    int j = tid & 7;
    int oc = (tid >> 3) & 255;
    int c = (tid >> 11) & 3;
    int hl = (tid >> 13) & 1;
    int step = tid >> 14;
    int ktap = step >> 3;
    int ch = ((step & 7) << 5) + (c << 3) + j;
    float v = w[oc * 2304 + ch * 9 + ktap] * 64.f;
    unsigned int h, l;
    split_f16_bits(v, h, l);
    bw2[tid] = (unsigned short)(hl ? l : h);
}

// ---- main (un-pipelined, prep-fed) ----
__global__ __launch_bounds__(256, 2) void k_dcn_v7(
    const float* __restrict__ offset,  // (8,18,64,64)
    const float* __restrict__ mask,    // (8,9,64,64)
    const float* __restrict__ bias,    // (256,)
    const float* __restrict__ xtf,     // (8,4096,256) f32
    const unsigned short* __restrict__ bw2,  // (72,2,4,256,8) fp16
    float* __restrict__ out)           // (8,256,64,64)
{
    // B tile: [hl2(+2112)][chunk4(stride 528)][pos64][8]; 4224 ush = 8.4 KB
    __shared__ __align__(16) unsigned short Bs[4224];

    const int t = threadIdx.x;
    const int tile = blockIdx.x;   // 512
    const int b = tile & 7;        // XCD/L2 locality
    const int ho = tile >> 3;      // 0..63

    const int lane = t & 63, wid = t >> 6, quad = lane >> 4, l15 = lane & 15;
    const int gpos = t >> 2, gseg = t & 3;
    const int wo = gpos;
    const int spos = (ho << 6) + wo;
    const float* xb = xtf + ((size_t)b << 20);

    // A fragment base (ush): [step][hl][chunk=quad][oc][8], oc = wid*64 + i*16 + l15
    const unsigned short* aBase = bw2 + quad * 2048 + (((wid << 6) + l15) << 3);

    floatx4 acc[4][4];
#pragma unroll
    for (int i = 0; i < 4; i++)
#pragma unroll
        for (int j = 0; j < 4; j++) acc[i][j] = (floatx4){0.f, 0.f, 0.f, 0.f};

    int yx00, yx01, yx10, yx11;
    float w00, w01, w10, w11;

    for (int kk = 0; kk < 72; ++kk) {
        // ---- coords at tap boundary (direct loads, no prefetch chain) ----
        if ((kk & 7) == 0) {
            const int tap = kk >> 3;
            float oy = offset[((size_t)(b * 18 + 2 * tap) << 12) + spos];
            float ox = offset[((size_t)(b * 18 + 2 * tap + 1) << 12) + spos];
            float mm = mask[((size_t)(b * 9 + tap) << 12) + spos];
            mk_coords(tap, ho, wo, oy, ox, mm,
                      yx00, yx01, yx10, yx11, w00, w01, w10, w11);
        }

        // ---- corners from xtf (this thread's 8-channel group) ----
        const int cb = ((kk & 7) << 5) + (gseg << 3);
        const float* p00 = xb + ((size_t)yx00 << 8) + cb;
        const float* p01 = xb + ((size_t)yx01 << 8) + cb;
        const float* p10 = xb + ((size_t)yx10 << 8) + cb;
        const float* p11 = xb + ((size_t)yx11 << 8) + cb;
        floatx4 c00a = *(const floatx4*)p00, c00b = *(const floatx4*)(p00 + 4);
        floatx4 c01a = *(const floatx4*)p01, c01b = *(const floatx4*)(p01 + 4);
        floatx4 c10a = *(const floatx4*)p10, c10b = *(const floatx4*)(p10 + 4);
        floatx4 c11a = *(const floatx4*)p11, c11b = *(const floatx4*)(p11 + 4);

        // ---- bilinear + fp16 split/pack -> Bs ----
        float vals[8];
#pragma unroll
        for (int q = 0; q < 4; q++) {
            vals[q]     = w00 * c00a[q] + w01 * c01a[q] + w10 * c10a[q] + w11 * c11a[q];
            vals[4 + q] = w00 * c00b[q] + w01 * c01b[q] + w10 * c10b[q] + w11 * c11b[q];
        }
        uintx4 pkH, pkL;
        split_pack8(vals, pkH, pkL);
        unsigned short* bp = Bs + gseg * 528 + (gpos << 3);
        *(uintx4*)bp = pkH;
        *(uintx4*)(bp + 2112) = pkL;

        // ---- A fragments from bw2 (registers, no LDS) ----
        const unsigned short* ap = aBase + (size_t)kk * 16384;
        half8 aH[4], aL[4];
#pragma unroll
        for (int i = 0; i < 4; i++) {
            aH[i] = *(const half8*)(ap + i * 128);
            aL[i] = *(const half8*)(ap + 8192 + i * 128);
        }

        __syncthreads();

        // ---- MFMA section ----
        const unsigned short* Bp = Bs + quad * 528;
        half8 bH[4], bL[4];
#pragma unroll
        for (int j = 0; j < 4; j++) {
            const int ro = ((j << 4) + l15) << 3;
            bH[j] = *(const half8*)(Bp + ro);
            bL[j] = *(const half8*)(Bp + 2112 + ro);
        }
#pragma unroll
        for (int i = 0; i < 4; i++)
#pragma unroll
            for (int j = 0; j < 4; j++) {
                acc[i][j] = MFMA16(aH[i], bH[j], acc[i][j]);
                acc[i][j] = MFMA16(aL[i], bH[j], acc[i][j]);
                acc[i][j] = MFMA16(aH[i], bL[j], acc[i][j]);
            }

        __syncthreads();
    }

    // ---- epilogue: C/D col=lane&15 -> pos, row=quad*4+r -> oc; undo x64 ----
    float* outb = out + ((size_t)b << 20);
    const int posbase = ho << 6;
#pragma unroll
    for (int i = 0; i < 4; i++) {
        const int ocb = (wid << 6) + (i << 4) + (quad << 2);
#pragma unroll
        for (int r = 0; r < 4; r++) {
            const float bv = bias[ocb + r];
#pragma unroll
            for (int j = 0; j < 4; j++) {
                const int pos = posbase + (j << 4) + l15;
                outb[((size_t)(ocb + r) << 12) + pos] = acc[i][j][r] * 0.015625f + bv;
            }
        }
    }
}

// ---- fallback (no workspace): R8-proven, byte-identical structure ----
__global__ __launch_bounds__(256, 2) void k_dcn_fb(
    const float* __restrict__ x, const float* __restrict__ offset,
    const float* __restrict__ mask, const float* __restrict__ weight,
    const float* __restrict__ bias, float* __restrict__ out)
{
    __shared__ __align__(16) unsigned short AsH[256 * 40];
    __shared__ __align__(16) unsigned short AsL[256 * 40];
    __shared__ __align__(16) unsigned short BsH[64 * 40];
    __shared__ __align__(16) unsigned short BsL[64 * 40];
    __shared__ int cY[64][4];
    __shared__ float cW[64][4];

    const int t = threadIdx.x;
    const int tile = blockIdx.x;   // 512
    const int b = tile >> 6;
    const int ho = tile & 63;
    const int lane = t & 63, wid = t >> 6, quad = lane >> 4, l15 = lane & 15;
    const int gpos = t >> 2, gseg = t & 3;

    floatx4 acc[4][4];
#pragma unroll
    for (int i = 0; i < 4; i++)
#pragma unroll
        for (int j = 0; j < 4; j++) acc[i][j] = (floatx4){0.f, 0.f, 0.f, 0.f};

    for (int ktap = 0; ktap < 9; ++ktap) {
        __syncthreads();
        if (t < 64) {
            int wo = t;
            int spos = (ho << 6) + wo;
            float offy = offset[(((size_t)(b * 18 + 2 * ktap)) << 12) + spos];
            float offx = offset[(((size_t)(b * 18 + 2 * ktap + 1)) << 12) + spos];
            float m = mask[(((size_t)(b * 9 + ktap)) << 12) + spos];
            int c0, c1, c2, c3; float u0, u1, u2, u3;
            mk_coords(ktap, ho, wo, offy, offx, m, c0, c1, c2, c3, u0, u1, u2, u3);
            cY[t][0] = c0; cY[t][1] = c1; cY[t][2] = c2; cY[t][3] = c3;
            cW[t][0] = u0; cW[t][1] = u1; cW[t][2] = u2; cW[t][3] = u3;
        }
        __syncthreads();
        const int yx00 = cY[gpos][0], yx01 = cY[gpos][1];
        const int yx10 = cY[gpos][2], yx11 = cY[gpos][3];
        const float w00 = cW[gpos][0], w01 = cW[gpos][1];
        const float w10 = cW[gpos][2], w11 = cW[gpos][3];

        for (int cs = 0; cs < 8; ++cs) {
            const int c0 = cs << 5;
            {
                const float* wp = weight + (size_t)t * 2304 + (size_t)c0 * 9 + ktap;
#pragma unroll
                for (int kj = 0; kj < 32; kj += 2) {
                    unsigned int h0, l0u, h1, l1u;
                    split_f16_bits(wp[kj * 9] * 64.f, h0, l0u);
                    split_f16_bits(wp[kj * 9 + 9] * 64.f, h1, l1u);
                    *(unsigned int*)&AsH[t * 40 + kj] = h0 | (h1 << 16);
                    *(unsigned int*)&AsL[t * 40 + kj] = l0u | (l1u << 16);
                }
            }
            {
                const int cb = c0 + (gseg << 3);
                const float* xg = x + ((size_t)b << 20);
                float vals[8];
#pragma unroll
                for (int j = 0; j < 8; j++) {
                    const float* xc = xg + ((size_t)(cb + j) << 12);
                    vals[j] = w00 * xc[yx00] + w01 * xc[yx01] +
                              w10 * xc[yx10] + w11 * xc[yx11];
                }
                uintx4 pkH, pkL;
                split_pack8(vals, pkH, pkL);
                *(uintx4*)&BsH[gpos * 40 + (gseg << 3)] = pkH;
                *(uintx4*)&BsL[gpos * 40 + (gseg << 3)] = pkL;
            }
            __syncthreads();
            half8 aH[4], aL[4], bH[4], bL[4];
#pragma unroll
            for (int i = 0; i < 4; i++) {
                const int rowA = (wid << 6) + (i << 4) + l15;
                aH[i] = *(const half8*)&AsH[rowA * 40 + (quad << 3)];
                aL[i] = *(const half8*)&AsL[rowA * 40 + (quad << 3)];
            }
#pragma unroll
            for (int j = 0; j < 4; j++) {
                const int rowB = (j << 4) + l15;
                bH[j] = *(const half8*)&BsH[rowB * 40 + (quad << 3)];
                bL[j] = *(const half8*)&BsL[rowB * 40 + (quad << 3)];
            }
#pragma unroll
            for (int i = 0; i < 4; i++)
#pragma unroll
                for (int j = 0; j < 4; j++) {
                    acc[i][j] = MFMA16(aH[i], bH[j], acc[i][j]);
                    acc[i][j] = MFMA16(aL[i], bH[j], acc[i][j]);
                    acc[i][j] = MFMA16(aH[i], bL[j], acc[i][j]);
                }
            __syncthreads();
        }
    }
    float* outb = out + ((size_t)b << 20);
    const int posbase = ho << 6;
#pragma unroll
    for (int i = 0; i < 4; i++) {
        const int ocb = (wid << 6) + (i << 4) + (quad << 2);
#pragma unroll
        for (int r = 0; r < 4; r++) {
            const float bv = bias[ocb + r];
#pragma unroll
            for (int j = 0; j < 4; j++) {
                const int pos = posbase + (j << 4) + l15;
                outb[((size_t)(ocb + r) << 12) + pos] = acc[i][j][r] * 0.015625f + bv;
            }
        }
    }
}

extern "C" void kernel_launch(void* const* d_in, const int* in_sizes, int n_in,
                              void* d_out, int out_size, void* d_ws, size_t ws_size,
                              hipStream_t stream) {
    const float* x      = (const float*)d_in[0];
    const float* offset = (const float*)d_in[1];
    const float* mask   = (const float*)d_in[2];
    const float* weight = (const float*)d_in[3];
    const float* bias   = (const float*)d_in[4];
    float* out = (float*)d_out;

    const size_t xtf_bytes = (size_t)8 * 4096 * 256 * 4;       // 32 MB
    const size_t bw2_elems = (size_t)72 * 16384;               // 1179648 ush
    const size_t need = xtf_bytes + bw2_elems * 2;             // ~34.25 MB

    if (ws_size >= need) {
        float* xtf = (float*)d_ws;
        unsigned short* bw2 = (unsigned short*)((char*)d_ws + xtf_bytes);
        k_prep_xt<<<2048, 256, 0, stream>>>(x, xtf);
        k_prep_w2<<<(int)(bw2_elems / 256), 256, 0, stream>>>(weight, bw2);
        k_dcn_v7<<<512, 256, 0, stream>>>(offset, mask, bias, xtf, bw2, out);
    } else {
        k_dcn_fb<<<512, 256, 0, stream>>>(x, offset, mask, weight, bias, out);
    }
}